// Round 5
// baseline (234.407 us; speedup 1.0000x reference)
//
#include <hip/hip_runtime.h>

#define P 10
#define D 1024
#define NROWS 16384
#define R 4                       // rows per thread

typedef float nfloat4 __attribute__((ext_vector_type(4)));   // clang-native for nontemporal builtins

// ---------------------------------------------------------------------------
// Column mapping (unchanged from round 4):
//   k = e_hi*256 + lane*4 + e_lo,  e = e_hi*4 + e_lo,  e in [0,16), lane in [0,64)
//   stage j flips bit j of k:
//     j=0,1  -> e_lo bits -> intra-thread (partner e^1 / e^2)
//     j=2..7 -> lane bits -> __shfl_xor mask 1<<(j-2)
//     j=8,9  -> e_hi bits -> intra-thread (partner e^4 / e^8)
// Coef table swizzled: coef[j*D + e*64 + lane] = (u_re,u_im,v_re,v_im) for k(e,lane).
// psi folded into stage-9 coefs. Each coef load now feeds R=4 rows.
// ---------------------------------------------------------------------------
__global__ void coef_kernel(const float* __restrict__ theta,
                            const float* __restrict__ phi,
                            const float* __restrict__ psi,
                            float4* __restrict__ coef) {
    int idx = blockIdx.x * blockDim.x + threadIdx.x;
    if (idx >= P * D) return;
    int j = idx >> 10;
    int slot = idx & (D - 1);
    int e = slot >> 6;
    int lane = slot & 63;
    int k = ((e >> 2) << 8) + (lane << 2) + (e & 3);   // column this slot serves
    int b = (k >> j) & 1;
    unsigned lowmask = (1u << j) - 1u;
    unsigned m = ((unsigned)k & lowmask) | (((unsigned)k >> 1) & ~lowmask); // delete bit j
    float th = theta[j * (D / 2) + m];
    float ph = phi[j * (D / 2) + m];
    float h = th * 0.5f;
    float s1 = sinf(h), c1 = cosf(h);
    float s2 = sinf(h + ph), c2 = cosf(h + ph);
    float ur, ui, vr, vi;
    if (b) { ur =  s1 * s1; vr = -c1 * s2; ui = -c1 * s1; vi = c1 * c2; }
    else   { ur = -s1 * s2; vr = -c1 * s1; ui =  s1 * c2; vi = c1 * c1; }
    if (j == P - 1) {
        float ps = psi[k];
        float cp = cosf(ps), sp = sinf(ps);
        float ur2 = cp * ur - sp * ui, ui2 = sp * ur + cp * ui;
        float vr2 = cp * vr - sp * vi, vi2 = sp * vr + cp * vi;
        ur = ur2; ui = ui2; vr = vr2; vi = vi2;
    }
    coef[idx] = make_float4(ur, ui, vr, vi);
}

// ---------------------------------------------------------------------------
// Intra-thread butterfly stage over R rows: partner differs in bit PM of e.
// One coef pair load serves all R rows.
// ---------------------------------------------------------------------------
template <int J, int PM>
__device__ __forceinline__ void stage_intra(float (&re)[R][16], float (&im)[R][16],
                                            const float4* __restrict__ coef, int lane) {
    const float4* cj = coef + J * D + lane;
#pragma unroll
    for (int e0 = 0; e0 < 16; ++e0) {
        if (e0 & PM) continue;
        const int e1 = e0 | PM;
        float4 c0 = cj[e0 * 64];
        float4 c1 = cj[e1 * 64];
#pragma unroll
        for (int r = 0; r < R; ++r) {
            float ar0 = re[r][e0], ai0 = im[r][e0], ar1 = re[r][e1], ai1 = im[r][e1];
            re[r][e0] = c0.x * ar0 - c0.y * ai0 + c0.z * ar1 - c0.w * ai1;
            im[r][e0] = c0.x * ai0 + c0.y * ar0 + c0.z * ai1 + c0.w * ar1;
            re[r][e1] = c1.x * ar1 - c1.y * ai1 + c1.z * ar0 - c1.w * ai0;
            im[r][e1] = c1.x * ai1 + c1.y * ar1 + c1.z * ai0 + c1.w * ar0;
        }
    }
}

// ---------------------------------------------------------------------------
// Cross-lane butterfly stage over R rows: partner differs in lane bit (J-2).
// One coef load per e serves all R rows.
// ---------------------------------------------------------------------------
template <int J>
__device__ __forceinline__ void stage_shfl(float (&re)[R][16], float (&im)[R][16],
                                           const float4* __restrict__ coef, int lane) {
    const int mask = 1 << (J - 2);
    const float4* cj = coef + J * D + lane;
#pragma unroll
    for (int e = 0; e < 16; ++e) {
        float4 c = cj[e * 64];
#pragma unroll
        for (int r = 0; r < R; ++r) {
            float sre = __shfl_xor(re[r][e], mask);
            float sim = __shfl_xor(im[r][e], mask);
            float nre = c.x * re[r][e] - c.y * im[r][e] + c.z * sre - c.w * sim;
            float nim = c.x * im[r][e] + c.y * re[r][e] + c.z * sim + c.w * sre;
            re[r][e] = nre; im[r][e] = nim;
        }
    }
}

__global__ __launch_bounds__(256) void fft_kernel(const float* __restrict__ X,
                                                  const float4* __restrict__ coef,
                                                  float* __restrict__ out) {
    const int lane = threadIdx.x & 63;
    const int wave = threadIdx.x >> 6;
    const long rowbase = (long)blockIdx.x * (4 * R) + (long)wave * R;
    const float* xb = X + rowbase * 2048 + lane * 4;

    float re[R][16], im[R][16];
#pragma unroll
    for (int r = 0; r < R; ++r) {
        const float* xr = xb + r * 2048;
#pragma unroll
        for (int eh = 0; eh < 4; ++eh) {
            float4 vr = *(const float4*)(xr + eh * 256);
            float4 vi = *(const float4*)(xr + 1024 + eh * 256);
            re[r][eh * 4 + 0] = vr.x; re[r][eh * 4 + 1] = vr.y;
            re[r][eh * 4 + 2] = vr.z; re[r][eh * 4 + 3] = vr.w;
            im[r][eh * 4 + 0] = vi.x; im[r][eh * 4 + 1] = vi.y;
            im[r][eh * 4 + 2] = vi.z; im[r][eh * 4 + 3] = vi.w;
        }
    }

    stage_intra<0, 1>(re, im, coef, lane);
    stage_intra<1, 2>(re, im, coef, lane);

    stage_shfl<2>(re, im, coef, lane);
    stage_shfl<3>(re, im, coef, lane);
    stage_shfl<4>(re, im, coef, lane);
    stage_shfl<5>(re, im, coef, lane);
    stage_shfl<6>(re, im, coef, lane);
    stage_shfl<7>(re, im, coef, lane);

    stage_intra<8, 4>(re, im, coef, lane);
    stage_intra<9, 8>(re, im, coef, lane);

    float* ob = out + rowbase * 2048 + lane * 4;
#pragma unroll
    for (int r = 0; r < R; ++r) {
        float* orow = ob + r * 2048;
#pragma unroll
        for (int eh = 0; eh < 4; ++eh) {
            nfloat4 vr = { re[r][eh * 4 + 0], re[r][eh * 4 + 1], re[r][eh * 4 + 2], re[r][eh * 4 + 3] };
            nfloat4 vi = { im[r][eh * 4 + 0], im[r][eh * 4 + 1], im[r][eh * 4 + 2], im[r][eh * 4 + 3] };
            __builtin_nontemporal_store(vr, (nfloat4*)(orow + eh * 256));
            __builtin_nontemporal_store(vi, (nfloat4*)(orow + 1024 + eh * 256));
        }
    }
}

extern "C" void kernel_launch(void* const* d_in, const int* in_sizes, int n_in,
                              void* d_out, int out_size, void* d_ws, size_t ws_size,
                              hipStream_t stream) {
    const float* X     = (const float*)d_in[0];
    const float* theta = (const float*)d_in[1];
    const float* phi   = (const float*)d_in[2];
    const float* psi   = (const float*)d_in[3];
    float4* coef = (float4*)d_ws;   // P*D*sizeof(float4) = 160 KB

    coef_kernel<<<(P * D + 255) / 256, 256, 0, stream>>>(theta, phi, psi, coef);
    fft_kernel<<<NROWS / (4 * R), 256, 0, stream>>>(X, coef, (float*)d_out);
}

// Round 6
// 106.370 us; speedup vs baseline: 2.2037x; 2.2037x over previous
//
#include <hip/hip_runtime.h>

#define P 10
#define D 1024
#define NROWS 16384

typedef float nfloat4 __attribute__((ext_vector_type(4)));   // clang-native for nontemporal builtins

// ---------------------------------------------------------------------------
// Column mapping (unchanged):
//   k = e_hi*256 + lane*4 + e_lo,  e = e_hi*4 + e_lo,  e in [0,16), lane in [0,64)
//   stage j flips bit j of k:
//     j=0,1  -> e_lo bits -> intra-thread (partner e^1 / e^2)
//     j=2..7 -> lane bits -> __shfl_xor mask 1<<(j-2)
//     j=8,9  -> e_hi bits -> intra-thread (partner e^4 / e^8)
// Coef table swizzled: coef[j*D + e*64 + lane] = (u_re,u_im,v_re,v_im) for k(e,lane).
// psi folded into stage-9 coefs.
//
// NEW this round: per-stage coef slab (16 KB) staged into double-buffered LDS
// by the whole block (T14 issue-early/write-late), so coef traffic hits L2
// once per BLOCK per stage instead of once per WAVE per stage (4x cut), and
// in-chain coef reads become ds_read_b128.
// ---------------------------------------------------------------------------
__global__ void coef_kernel(const float* __restrict__ theta,
                            const float* __restrict__ phi,
                            const float* __restrict__ psi,
                            float4* __restrict__ coef) {
    int idx = blockIdx.x * blockDim.x + threadIdx.x;
    if (idx >= P * D) return;
    int j = idx >> 10;
    int slot = idx & (D - 1);
    int e = slot >> 6;
    int lane = slot & 63;
    int k = ((e >> 2) << 8) + (lane << 2) + (e & 3);   // column this slot serves
    int b = (k >> j) & 1;
    unsigned lowmask = (1u << j) - 1u;
    unsigned m = ((unsigned)k & lowmask) | (((unsigned)k >> 1) & ~lowmask); // delete bit j
    float th = theta[j * (D / 2) + m];
    float ph = phi[j * (D / 2) + m];
    float h = th * 0.5f;
    float s1 = sinf(h), c1 = cosf(h);
    float s2 = sinf(h + ph), c2 = cosf(h + ph);
    float ur, ui, vr, vi;
    if (b) { ur =  s1 * s1; vr = -c1 * s2; ui = -c1 * s1; vi = c1 * c2; }
    else   { ur = -s1 * s2; vr = -c1 * s1; ui =  s1 * c2; vi = c1 * c1; }
    if (j == P - 1) {
        float ps = psi[k];
        float cp = cosf(ps), sp = sinf(ps);
        float ur2 = cp * ur - sp * ui, ui2 = sp * ur + cp * ui;
        float vr2 = cp * vr - sp * vi, vi2 = sp * vr + cp * vi;
        ur = ur2; ui = ui2; vr = vr2; vi = vi2;
    }
    coef[idx] = make_float4(ur, ui, vr, vi);
}

// ---------------------------------------------------------------------------
// Butterfly stages, coefs read from LDS slab (lsrc = current stage's buffer).
// ---------------------------------------------------------------------------
template <int PM>
__device__ __forceinline__ void stage_intra(float (&ra)[16], float (&ia)[16],
                                            float (&rb)[16], float (&ib)[16],
                                            const float4* lsrc, int lane) {
#pragma unroll
    for (int e0 = 0; e0 < 16; ++e0) {
        if (e0 & PM) continue;
        const int e1 = e0 | PM;
        float4 c0 = lsrc[e0 * 64 + lane];
        float4 c1 = lsrc[e1 * 64 + lane];
        float ar0 = ra[e0], ai0 = ia[e0], ar1 = ra[e1], ai1 = ia[e1];
        float br0 = rb[e0], bi0 = ib[e0], br1 = rb[e1], bi1 = ib[e1];
        ra[e0] = c0.x * ar0 - c0.y * ai0 + c0.z * ar1 - c0.w * ai1;
        ia[e0] = c0.x * ai0 + c0.y * ar0 + c0.z * ai1 + c0.w * ar1;
        ra[e1] = c1.x * ar1 - c1.y * ai1 + c1.z * ar0 - c1.w * ai0;
        ia[e1] = c1.x * ai1 + c1.y * ar1 + c1.z * ai0 + c1.w * ar0;
        rb[e0] = c0.x * br0 - c0.y * bi0 + c0.z * br1 - c0.w * bi1;
        ib[e0] = c0.x * bi0 + c0.y * br0 + c0.z * bi1 + c0.w * br1;
        rb[e1] = c1.x * br1 - c1.y * bi1 + c1.z * br0 - c1.w * bi0;
        ib[e1] = c1.x * bi1 + c1.y * br1 + c1.z * bi0 + c1.w * br0;
    }
}

template <int MASK>
__device__ __forceinline__ void stage_shfl(float (&ra)[16], float (&ia)[16],
                                           float (&rb)[16], float (&ib)[16],
                                           const float4* lsrc, int lane) {
#pragma unroll
    for (int e = 0; e < 16; ++e) {
        float4 c = lsrc[e * 64 + lane];
        float sra = __shfl_xor(ra[e], MASK);
        float sia = __shfl_xor(ia[e], MASK);
        float srb = __shfl_xor(rb[e], MASK);
        float sib = __shfl_xor(ib[e], MASK);
        float nra = c.x * ra[e] - c.y * ia[e] + c.z * sra - c.w * sia;
        float nia = c.x * ia[e] + c.y * ra[e] + c.z * sia + c.w * sra;
        float nrb = c.x * rb[e] - c.y * ib[e] + c.z * srb - c.w * sib;
        float nib = c.x * ib[e] + c.y * rb[e] + c.z * sib + c.w * srb;
        ra[e] = nra; ia[e] = nia; rb[e] = nrb; ib[e] = nib;
    }
}

// Issue next stage's global coef loads (early — latency hides under compute).
__device__ __forceinline__ void pre_load(const float4* __restrict__ coef, int j,
                                         int tid, float4 (&st)[4]) {
#pragma unroll
    for (int i = 0; i < 4; ++i) st[i] = coef[j * D + i * 256 + tid];
}

// Write staged coefs to the LDS buffer and barrier (late — after compute).
__device__ __forceinline__ void commit(float4* dst, int tid, const float4 (&st)[4]) {
#pragma unroll
    for (int i = 0; i < 4; ++i) dst[i * 256 + tid] = st[i];
    __syncthreads();
}

__global__ __launch_bounds__(256) void fft_kernel(const float* __restrict__ X,
                                                  const float4* __restrict__ coef,
                                                  float* __restrict__ out) {
    __shared__ float4 lc[2][D];            // 32 KB double buffer
    const int tid  = threadIdx.x;
    const int lane = tid & 63;
    const int wave = tid >> 6;
    const long rowbase = (long)blockIdx.x * 8 + (long)wave * 2;
    const float* x0 = X + rowbase * 2048 + lane * 4;
    const float* x1 = x0 + 2048;

    // X loads issued up front (independent of staging)
    float ra[16], ia[16], rb[16], ib[16];
#pragma unroll
    for (int eh = 0; eh < 4; ++eh) {
        float4 v0r = *(const float4*)(x0 + eh * 256);
        float4 v0i = *(const float4*)(x0 + 1024 + eh * 256);
        float4 v1r = *(const float4*)(x1 + eh * 256);
        float4 v1i = *(const float4*)(x1 + 1024 + eh * 256);
        ra[eh * 4 + 0] = v0r.x; ra[eh * 4 + 1] = v0r.y; ra[eh * 4 + 2] = v0r.z; ra[eh * 4 + 3] = v0r.w;
        ia[eh * 4 + 0] = v0i.x; ia[eh * 4 + 1] = v0i.y; ia[eh * 4 + 2] = v0i.z; ia[eh * 4 + 3] = v0i.w;
        rb[eh * 4 + 0] = v1r.x; rb[eh * 4 + 1] = v1r.y; rb[eh * 4 + 2] = v1r.z; rb[eh * 4 + 3] = v1r.w;
        ib[eh * 4 + 0] = v1i.x; ib[eh * 4 + 1] = v1i.y; ib[eh * 4 + 2] = v1i.z; ib[eh * 4 + 3] = v1i.w;
    }

    float4 st[4];
    // Pipeline: PRE(j+1) -> compute stage j from buf[j&1] -> commit to buf[(j+1)&1] + barrier.
    pre_load(coef, 0, tid, st); commit(&lc[0][0], tid, st);
    pre_load(coef, 1, tid, st); stage_intra<1>(ra, ia, rb, ib, &lc[0][0], lane); commit(&lc[1][0], tid, st);
    pre_load(coef, 2, tid, st); stage_intra<2>(ra, ia, rb, ib, &lc[1][0], lane); commit(&lc[0][0], tid, st);
    pre_load(coef, 3, tid, st); stage_shfl<1>(ra, ia, rb, ib, &lc[0][0], lane);  commit(&lc[1][0], tid, st);
    pre_load(coef, 4, tid, st); stage_shfl<2>(ra, ia, rb, ib, &lc[1][0], lane);  commit(&lc[0][0], tid, st);
    pre_load(coef, 5, tid, st); stage_shfl<4>(ra, ia, rb, ib, &lc[0][0], lane);  commit(&lc[1][0], tid, st);
    pre_load(coef, 6, tid, st); stage_shfl<8>(ra, ia, rb, ib, &lc[1][0], lane);  commit(&lc[0][0], tid, st);
    pre_load(coef, 7, tid, st); stage_shfl<16>(ra, ia, rb, ib, &lc[0][0], lane); commit(&lc[1][0], tid, st);
    pre_load(coef, 8, tid, st); stage_shfl<32>(ra, ia, rb, ib, &lc[1][0], lane); commit(&lc[0][0], tid, st);
    pre_load(coef, 9, tid, st); stage_intra<4>(ra, ia, rb, ib, &lc[0][0], lane); commit(&lc[1][0], tid, st);
    stage_intra<8>(ra, ia, rb, ib, &lc[1][0], lane);

    float* o0 = out + rowbase * 2048 + lane * 4;
    float* o1 = o0 + 2048;
#pragma unroll
    for (int eh = 0; eh < 4; ++eh) {
        nfloat4 v0r = { ra[eh * 4 + 0], ra[eh * 4 + 1], ra[eh * 4 + 2], ra[eh * 4 + 3] };
        nfloat4 v0i = { ia[eh * 4 + 0], ia[eh * 4 + 1], ia[eh * 4 + 2], ia[eh * 4 + 3] };
        nfloat4 v1r = { rb[eh * 4 + 0], rb[eh * 4 + 1], rb[eh * 4 + 2], rb[eh * 4 + 3] };
        nfloat4 v1i = { ib[eh * 4 + 0], ib[eh * 4 + 1], ib[eh * 4 + 2], ib[eh * 4 + 3] };
        __builtin_nontemporal_store(v0r, (nfloat4*)(o0 + eh * 256));
        __builtin_nontemporal_store(v0i, (nfloat4*)(o0 + 1024 + eh * 256));
        __builtin_nontemporal_store(v1r, (nfloat4*)(o1 + eh * 256));
        __builtin_nontemporal_store(v1i, (nfloat4*)(o1 + 1024 + eh * 256));
    }
}

extern "C" void kernel_launch(void* const* d_in, const int* in_sizes, int n_in,
                              void* d_out, int out_size, void* d_ws, size_t ws_size,
                              hipStream_t stream) {
    const float* X     = (const float*)d_in[0];
    const float* theta = (const float*)d_in[1];
    const float* phi   = (const float*)d_in[2];
    const float* psi   = (const float*)d_in[3];
    float4* coef = (float4*)d_ws;   // P*D*sizeof(float4) = 160 KB

    coef_kernel<<<(P * D + 255) / 256, 256, 0, stream>>>(theta, phi, psi, coef);
    fft_kernel<<<NROWS / 8, 256, 0, stream>>>(X, coef, (float*)d_out);
}

// Round 7
// 79.212 us; speedup vs baseline: 2.9592x; 1.3429x over previous
//
#include <hip/hip_runtime.h>

#define P 10
#define D 1024
#define NROWS 16384

typedef float nfloat4 __attribute__((ext_vector_type(4)));   // clang-native for nontemporal builtins

// ---------------------------------------------------------------------------
// Column mapping (unchanged from round 4):
//   k = e_hi*256 + lane*4 + e_lo,  e = e_hi*4 + e_lo,  e in [0,16), lane in [0,64)
//   stage j flips bit j of k:
//     j=0,1  -> e_lo bits -> intra-thread (partner e^1 / e^2)
//     j=2..7 -> lane bits -> __shfl_xor mask 1<<(j-2)
//     j=8,9  -> e_hi bits -> intra-thread (partner e^4 / e^8)
// Coef table swizzled: coef[j*D + e*64 + lane] = (u_re,u_im,v_re,v_im) for k(e,lane).
// psi folded into stage-9 coefs.
//
// NEW this round: 16-slot register RING of current-stage coefs. Slot e is
// reloaded with stage j+1's coef immediately after its last use in stage j,
// so every coef load has ~1 full stage of compute in flight before use.
// No LDS, no barriers (r6 lesson), same load count as r4.
// ---------------------------------------------------------------------------
__global__ void coef_kernel(const float* __restrict__ theta,
                            const float* __restrict__ phi,
                            const float* __restrict__ psi,
                            float4* __restrict__ coef) {
    int idx = blockIdx.x * blockDim.x + threadIdx.x;
    if (idx >= P * D) return;
    int j = idx >> 10;
    int slot = idx & (D - 1);
    int e = slot >> 6;
    int lane = slot & 63;
    int k = ((e >> 2) << 8) + (lane << 2) + (e & 3);   // column this slot serves
    int b = (k >> j) & 1;
    unsigned lowmask = (1u << j) - 1u;
    unsigned m = ((unsigned)k & lowmask) | (((unsigned)k >> 1) & ~lowmask); // delete bit j
    float th = theta[j * (D / 2) + m];
    float ph = phi[j * (D / 2) + m];
    float h = th * 0.5f;
    float s1 = sinf(h), c1 = cosf(h);
    float s2 = sinf(h + ph), c2 = cosf(h + ph);
    float ur, ui, vr, vi;
    if (b) { ur =  s1 * s1; vr = -c1 * s2; ui = -c1 * s1; vi = c1 * c2; }
    else   { ur = -s1 * s2; vr = -c1 * s1; ui =  s1 * c2; vi = c1 * c1; }
    if (j == P - 1) {
        float ps = psi[k];
        float cp = cosf(ps), sp = sinf(ps);
        float ur2 = cp * ur - sp * ui, ui2 = sp * ur + cp * ui;
        float vr2 = cp * vr - sp * vi, vi2 = sp * vr + cp * vi;
        ur = ur2; ui = ui2; vr = vr2; vi = vi2;
    }
    coef[idx] = make_float4(ur, ui, vr, vi);
}

// ---------------------------------------------------------------------------
// Intra-thread stage with ring prefetch. PM = partner mask in e-space.
// NEXTJ = stage whose coefs refill the ring (-1: none).
// All cf indices are compile-time constants after unroll (no scratch).
// ---------------------------------------------------------------------------
template <int PM, int NEXTJ>
__device__ __forceinline__ void stage_intra(float (&ra)[16], float (&ia)[16],
                                            float (&rb)[16], float (&ib)[16],
                                            float4 (&cf)[16], const float4* cbase) {
#pragma unroll
    for (int e0 = 0; e0 < 16; ++e0) {
        if (e0 & PM) continue;
        const int e1 = e0 | PM;
        float4 c0 = cf[e0];
        float4 c1 = cf[e1];
        if (NEXTJ >= 0) {                       // refill freed slots early
            cf[e0] = cbase[NEXTJ * D + e0 * 64];
            cf[e1] = cbase[NEXTJ * D + e1 * 64];
        }
        float ar0 = ra[e0], ai0 = ia[e0], ar1 = ra[e1], ai1 = ia[e1];
        float br0 = rb[e0], bi0 = ib[e0], br1 = rb[e1], bi1 = ib[e1];
        ra[e0] = c0.x * ar0 - c0.y * ai0 + c0.z * ar1 - c0.w * ai1;
        ia[e0] = c0.x * ai0 + c0.y * ar0 + c0.z * ai1 + c0.w * ar1;
        ra[e1] = c1.x * ar1 - c1.y * ai1 + c1.z * ar0 - c1.w * ai0;
        ia[e1] = c1.x * ai1 + c1.y * ar1 + c1.z * ai0 + c1.w * ar0;
        rb[e0] = c0.x * br0 - c0.y * bi0 + c0.z * br1 - c0.w * bi1;
        ib[e0] = c0.x * bi0 + c0.y * br0 + c0.z * bi1 + c0.w * br1;
        rb[e1] = c1.x * br1 - c1.y * bi1 + c1.z * br0 - c1.w * bi0;
        ib[e1] = c1.x * bi1 + c1.y * br1 + c1.z * bi0 + c1.w * br0;
    }
}

// ---------------------------------------------------------------------------
// Cross-lane stage with ring prefetch. MASK = lane xor mask.
// ---------------------------------------------------------------------------
template <int MASK, int NEXTJ>
__device__ __forceinline__ void stage_shfl(float (&ra)[16], float (&ia)[16],
                                           float (&rb)[16], float (&ib)[16],
                                           float4 (&cf)[16], const float4* cbase) {
#pragma unroll
    for (int e = 0; e < 16; ++e) {
        float4 c = cf[e];
        if (NEXTJ >= 0) cf[e] = cbase[NEXTJ * D + e * 64];
        float sra = __shfl_xor(ra[e], MASK);
        float sia = __shfl_xor(ia[e], MASK);
        float srb = __shfl_xor(rb[e], MASK);
        float sib = __shfl_xor(ib[e], MASK);
        float nra = c.x * ra[e] - c.y * ia[e] + c.z * sra - c.w * sia;
        float nia = c.x * ia[e] + c.y * ra[e] + c.z * sia + c.w * sra;
        float nrb = c.x * rb[e] - c.y * ib[e] + c.z * srb - c.w * sib;
        float nib = c.x * ib[e] + c.y * rb[e] + c.z * sib + c.w * srb;
        ra[e] = nra; ia[e] = nia; rb[e] = nrb; ib[e] = nib;
    }
}

__global__ __launch_bounds__(256) void fft_kernel(const float* __restrict__ X,
                                                  const float4* __restrict__ coef,
                                                  float* __restrict__ out) {
    const int lane = threadIdx.x & 63;
    const int wave = threadIdx.x >> 6;
    const long rowbase = (long)blockIdx.x * 8 + (long)wave * 2;
    const float* x0 = X + rowbase * 2048 + lane * 4;
    const float* x1 = x0 + 2048;
    const float4* cbase = coef + lane;

    // X loads first (longest latency: HBM/L3)
    float ra[16], ia[16], rb[16], ib[16];
#pragma unroll
    for (int eh = 0; eh < 4; ++eh) {
        float4 v0r = *(const float4*)(x0 + eh * 256);
        float4 v0i = *(const float4*)(x0 + 1024 + eh * 256);
        float4 v1r = *(const float4*)(x1 + eh * 256);
        float4 v1i = *(const float4*)(x1 + 1024 + eh * 256);
        ra[eh * 4 + 0] = v0r.x; ra[eh * 4 + 1] = v0r.y; ra[eh * 4 + 2] = v0r.z; ra[eh * 4 + 3] = v0r.w;
        ia[eh * 4 + 0] = v0i.x; ia[eh * 4 + 1] = v0i.y; ia[eh * 4 + 2] = v0i.z; ia[eh * 4 + 3] = v0i.w;
        rb[eh * 4 + 0] = v1r.x; rb[eh * 4 + 1] = v1r.y; rb[eh * 4 + 2] = v1r.z; rb[eh * 4 + 3] = v1r.w;
        ib[eh * 4 + 0] = v1i.x; ib[eh * 4 + 1] = v1i.y; ib[eh * 4 + 2] = v1i.z; ib[eh * 4 + 3] = v1i.w;
    }

    // Prologue: fill the ring with stage-0 coefs
    float4 cf[16];
#pragma unroll
    for (int e = 0; e < 16; ++e) cf[e] = cbase[0 * D + e * 64];

    stage_intra<1, 1>(ra, ia, rb, ib, cf, cbase);   // stage 0, prefetch 1
    stage_intra<2, 2>(ra, ia, rb, ib, cf, cbase);   // stage 1, prefetch 2
    stage_shfl<1, 3>(ra, ia, rb, ib, cf, cbase);    // stage 2, prefetch 3
    stage_shfl<2, 4>(ra, ia, rb, ib, cf, cbase);    // stage 3, prefetch 4
    stage_shfl<4, 5>(ra, ia, rb, ib, cf, cbase);    // stage 4, prefetch 5
    stage_shfl<8, 6>(ra, ia, rb, ib, cf, cbase);    // stage 5, prefetch 6
    stage_shfl<16, 7>(ra, ia, rb, ib, cf, cbase);   // stage 6, prefetch 7
    stage_shfl<32, 8>(ra, ia, rb, ib, cf, cbase);   // stage 7, prefetch 8
    stage_intra<4, 9>(ra, ia, rb, ib, cf, cbase);   // stage 8, prefetch 9
    stage_intra<8, -1>(ra, ia, rb, ib, cf, cbase);  // stage 9, no prefetch

    float* o0 = out + rowbase * 2048 + lane * 4;
    float* o1 = o0 + 2048;
#pragma unroll
    for (int eh = 0; eh < 4; ++eh) {
        nfloat4 v0r = { ra[eh * 4 + 0], ra[eh * 4 + 1], ra[eh * 4 + 2], ra[eh * 4 + 3] };
        nfloat4 v0i = { ia[eh * 4 + 0], ia[eh * 4 + 1], ia[eh * 4 + 2], ia[eh * 4 + 3] };
        nfloat4 v1r = { rb[eh * 4 + 0], rb[eh * 4 + 1], rb[eh * 4 + 2], rb[eh * 4 + 3] };
        nfloat4 v1i = { ib[eh * 4 + 0], ib[eh * 4 + 1], ib[eh * 4 + 2], ib[eh * 4 + 3] };
        __builtin_nontemporal_store(v0r, (nfloat4*)(o0 + eh * 256));
        __builtin_nontemporal_store(v0i, (nfloat4*)(o0 + 1024 + eh * 256));
        __builtin_nontemporal_store(v1r, (nfloat4*)(o1 + eh * 256));
        __builtin_nontemporal_store(v1i, (nfloat4*)(o1 + 1024 + eh * 256));
    }
}

extern "C" void kernel_launch(void* const* d_in, const int* in_sizes, int n_in,
                              void* d_out, int out_size, void* d_ws, size_t ws_size,
                              hipStream_t stream) {
    const float* X     = (const float*)d_in[0];
    const float* theta = (const float*)d_in[1];
    const float* phi   = (const float*)d_in[2];
    const float* psi   = (const float*)d_in[3];
    float4* coef = (float4*)d_ws;   // P*D*sizeof(float4) = 160 KB

    coef_kernel<<<(P * D + 255) / 256, 256, 0, stream>>>(theta, phi, psi, coef);
    fft_kernel<<<NROWS / 8, 256, 0, stream>>>(X, coef, (float*)d_out);
}